// Round 4
// baseline (5147.992 us; speedup 1.0000x reference)
//
#include <hip/hip_runtime.h>
#include <hip/hip_fp16.h>

#define BB 64
#define SS 512
#define HH 1024
#define II 4096
#define EE 8

typedef _Float16 h8 __attribute__((ext_vector_type(8)));
typedef _Float16 h4 __attribute__((ext_vector_type(4)));
typedef float f4 __attribute__((ext_vector_type(4)));

typedef const __attribute__((address_space(1))) void* gas_t;
typedef __attribute__((address_space(3))) void* las_t;

__device__ __forceinline__ void gl_lds16(const void* g, void* l) {
  // async global->LDS, 16B per lane; LDS dest = wave-uniform base + lane*16
  __builtin_amdgcn_global_load_lds((gas_t)g, (las_t)l, 16, 0, 0);
}

// swizzled ELEMENT (fp16) offset into a [rows][32] fp16 tile.
// Staging puts global k-octet (s ^ ((row>>1)&3)) at LDS slot s; this inverts it.
__device__ __forceinline__ int swzE(int row, int kslot) {
  return row * 32 + (((kslot ^ (row >> 1)) & 3) << 3);
}

// T1: XCD-aware flat-block-id swizzle; requires nwg % 8 == 0 (always true here).
__device__ __forceinline__ int xcd_swz(int orig, int nwg) {
  return (orig & 7) * (nwg >> 3) + (orig >> 3);
}

// fast gelu(tanh-approx): g * sigmoid(1.5957692*(g + 0.044715 g^3))
__device__ __forceinline__ float fast_gelu(float g) {
  float t = 1.5957691216057308f * (g + 0.044715f * g * g * g);
  return g * __builtin_amdgcn_rcpf(1.0f + __expf(-t));
}

// ---------------- router: softmax -> top2 -> renormalize ----------------
__global__ void router_kernel(const float* __restrict__ logits,
                              int* __restrict__ sel, float* __restrict__ wsel) {
  int b = threadIdx.x;
  if (b >= BB) return;
  float l[EE];
  float mx = -1e30f;
  for (int e = 0; e < EE; ++e) { l[e] = logits[b * EE + e]; mx = fmaxf(mx, l[e]); }
  for (int e = 0; e < EE; ++e) l[e] = __expf(l[e] - mx);
  int i0 = 0;
  for (int e = 1; e < EE; ++e) if (l[e] > l[i0]) i0 = e;
  int i1 = (i0 == 0) ? 1 : 0;
  for (int e = 0; e < EE; ++e) if (e != i0 && l[e] > l[i1]) i1 = e;
  float t = l[i0] + l[i1];
  sel[b * 2 + 0] = i0; sel[b * 2 + 1] = i1;
  wsel[b * 2 + 0] = l[i0] / t; wsel[b * 2 + 1] = l[i1] / t;
}

// ---------------- x fp32 -> fp16 ----------------
__global__ void __launch_bounds__(256) cvt_x_kernel(const float* __restrict__ src,
                                                    _Float16* __restrict__ dst) {
  int i = blockIdx.x * 256 + threadIdx.x;
  const float4* s4 = (const float4*)src;
  float4 a = s4[2 * i], b = s4[2 * i + 1];
  h8 o = {(_Float16)a.x, (_Float16)a.y, (_Float16)a.z, (_Float16)a.w,
          (_Float16)b.x, (_Float16)b.y, (_Float16)b.z, (_Float16)b.w};
  *((h8*)dst + i) = o;
}

// ---------------- tiled transpose + fp32->fp16: src[R][C] -> dst[C][R] ----------------
__global__ void __launch_bounds__(256) tcvt_kernel(const float* __restrict__ src,
                                                   _Float16* __restrict__ dst,
                                                   int R, int C) {
  __shared__ float tile[32][33];
  size_t msz = (size_t)R * C;
  src += (size_t)blockIdx.z * msz;
  dst += (size_t)blockIdx.z * msz;
  int c0 = blockIdx.x * 32, r0 = blockIdx.y * 32;
  int t = threadIdx.x;
  int ir = t >> 3, ic = (t & 7) * 4;
  float4 v = *(const float4*)(src + (size_t)(r0 + ir) * C + c0 + ic);
  tile[ir][ic + 0] = v.x; tile[ir][ic + 1] = v.y;
  tile[ir][ic + 2] = v.z; tile[ir][ic + 3] = v.w;
  __syncthreads();
  h4 o;
  o[0] = (_Float16)tile[ic + 0][ir];
  o[1] = (_Float16)tile[ic + 1][ir];
  o[2] = (_Float16)tile[ic + 2][ir];
  o[3] = (_Float16)tile[ic + 3][ir];
  *(h4*)(dst + (size_t)(c0 + ir) * R + r0 + ic) = o;
}

// ---------------- up: G = x@Wg, U = x@Wu, h = wgt * gelu(G) * U ----------------
// 128x128 tile (G and U), BK=32, 4 waves, 2-phase double-buffered staging.
__global__ void __launch_bounds__(256)
moe_up_kernel(const _Float16* __restrict__ xf,
              const _Float16* __restrict__ sgT, const _Float16* __restrict__ suT,
              const _Float16* __restrict__ shgT, const _Float16* __restrict__ shuT,
              const int* __restrict__ sel, const float* __restrict__ wsel,
              _Float16* __restrict__ hbuf, int b0) {
  __shared__ _Float16 As[2][128 * 32];
  __shared__ _Float16 Bg[2][128 * 32];
  __shared__ _Float16 Bu[2][128 * 32];

  // XCD swizzle on flat id (x fastest): 768-block chunks = 6 whole tasks/XCD
  const int nz = gridDim.z;
  int orig = blockIdx.x + 4 * (blockIdx.y + 32 * blockIdx.z);
  int swz = xcd_swz(orig, 128 * nz);
  const int bm = swz & 3, bn = (swz >> 2) & 31, task = swz >> 7;

  const int cb = task / 3, slot = task - cb * 3;
  const int b = b0 + cb;
  const _Float16 *Wg, *Wu;
  float wgt;
  if (slot < 2) {
    int e = sel[b * 2 + slot];
    wgt = wsel[b * 2 + slot];
    Wg = sgT + (size_t)e * II * HH;
    Wu = suT + (size_t)e * II * HH;
  } else {
    wgt = 1.0f; Wg = shgT; Wu = shuT;
  }
  const _Float16* A = xf + (size_t)b * SS * HH;
  const int m0 = bm * 128, n0 = bn * 128;
  const int tid = threadIdx.x, lane = tid & 63, wv = tid >> 6;
  const int wm = (wv >> 1) * 64, wn = (wv & 1) * 64;

  const int sr = tid >> 2;
  const int ksl = (tid & 3) ^ ((tid >> 3) & 3);
  const _Float16* ga0 = A + (size_t)(m0 + sr) * HH + ksl * 8;
  const _Float16* ga1 = A + (size_t)(m0 + 64 + sr) * HH + ksl * 8;
  const _Float16* gg0 = Wg + (size_t)(n0 + sr) * HH + ksl * 8;
  const _Float16* gg1 = Wg + (size_t)(n0 + 64 + sr) * HH + ksl * 8;
  const _Float16* gu0 = Wu + (size_t)(n0 + sr) * HH + ksl * 8;
  const _Float16* gu1 = Wu + (size_t)(n0 + 64 + sr) * HH + ksl * 8;

  const int ra = lane & 15, kq = lane >> 4;
  f4 accG[4][4] = {};
  f4 accU[4][4] = {};

  auto stage = [&](int bb, int k0) {
    gl_lds16(ga0 + k0, &As[bb][wv * 512]);
    gl_lds16(ga1 + k0, &As[bb][2048 + wv * 512]);
    gl_lds16(gg0 + k0, &Bg[bb][wv * 512]);
    gl_lds16(gg1 + k0, &Bg[bb][2048 + wv * 512]);
    gl_lds16(gu0 + k0, &Bu[bb][wv * 512]);
    gl_lds16(gu1 + k0, &Bu[bb][2048 + wv * 512]);
  };
  auto compute = [&](int bb) {
    h8 af[4], bgf[4], buf_[4];
#pragma unroll
    for (int m = 0; m < 4; ++m) af[m] = *(const h8*)&As[bb][swzE(wm + m * 16 + ra, kq)];
#pragma unroll
    for (int n = 0; n < 4; ++n) {
      bgf[n] = *(const h8*)&Bg[bb][swzE(wn + n * 16 + ra, kq)];
      buf_[n] = *(const h8*)&Bu[bb][swzE(wn + n * 16 + ra, kq)];
    }
#pragma unroll
    for (int m = 0; m < 4; ++m)
#pragma unroll
      for (int n = 0; n < 4; ++n) {
        accG[m][n] = __builtin_amdgcn_mfma_f32_16x16x32_f16(af[m], bgf[n], accG[m][n], 0, 0, 0);
        accU[m][n] = __builtin_amdgcn_mfma_f32_16x16x32_f16(af[m], buf_[n], accU[m][n], 0, 0, 0);
      }
  };

  // 2-phase pipeline: issue next stage BEFORE compute; one barrier per step.
  stage(0, 0);
  __syncthreads();
  int cur = 0;
  for (int k0 = 32; k0 < HH; k0 += 32) {
    stage(cur ^ 1, k0);
    compute(cur);
    __syncthreads();
    cur ^= 1;
  }
  compute(cur);

  // epilogue: h = wgt * gelu(G) * U -> fp16
  _Float16* hb = hbuf + (size_t)task * SS * II;
  const int rr = wm + (lane >> 4) * 4;
  const int cc = n0 + wn + ra;
#pragma unroll
  for (int m = 0; m < 4; ++m)
#pragma unroll
    for (int n = 0; n < 4; ++n)
#pragma unroll
      for (int r = 0; r < 4; ++r) {
        float g = accG[m][n][r];
        float u = accU[m][n][r];
        int row = m0 + rr + m * 16 + r;
        int col = cc + n * 16;
        hb[(size_t)row * II + col] = (_Float16)(wgt * fast_gelu(g) * u);
      }
}

// ---------------- down: out[b] = sum_slot h_slot @ Wd_slot ----------------
// 128x128 tile, BK=32, flattened 384-step 2-phase pipeline across 3 slots.
__global__ void __launch_bounds__(256)
moe_down_kernel(const _Float16* __restrict__ hbuf,
                const _Float16* __restrict__ sdT, const _Float16* __restrict__ shdT,
                const int* __restrict__ sel,
                float* __restrict__ out, int b0) {
  __shared__ _Float16 As[2][128 * 32];
  __shared__ _Float16 Bs[2][128 * 32];

  const int nz = gridDim.z;
  int orig = blockIdx.x + 4 * (blockIdx.y + 8 * blockIdx.z);
  int swz = xcd_swz(orig, 32 * nz);
  const int bm = swz & 3, bn = (swz >> 2) & 7, cb = swz >> 5;
  const int b = b0 + cb;

  const int m0 = bm * 128, n0 = bn * 128;
  const int tid = threadIdx.x, lane = tid & 63, wv = tid >> 6;
  const int wm = (wv >> 1) * 64, wn = (wv & 1) * 64;
  const int sr = tid >> 2;
  const int ksl = (tid & 3) ^ ((tid >> 3) & 3);
  const int ra = lane & 15, kq = lane >> 4;

  const size_t slotStride = (size_t)SS * II;
  const _Float16* a0 = hbuf + (size_t)(cb * 3) * slotStride + (size_t)(m0 + sr) * II + ksl * 8;
  const size_t bof = (size_t)(n0 + sr) * II + ksl * 8;
  const _Float16* pb0 = sdT + (size_t)sel[b * 2 + 0] * HH * II + bof;
  const _Float16* pb1 = sdT + (size_t)sel[b * 2 + 1] * HH * II + bof;
  const _Float16* pb2 = shdT + bof;

  f4 acc[4][4] = {};

  auto stage = [&](int bb, int t) {
    int slot = t >> 7;                 // 128 K-steps per slot
    int k0 = (t & 127) << 5;
    const _Float16* A0 = a0 + (size_t)slot * slotStride + k0;
    const _Float16* Bp = (slot == 0 ? pb0 : (slot == 1 ? pb1 : pb2)) + k0;
    gl_lds16(A0, &As[bb][wv * 512]);
    gl_lds16(A0 + (size_t)64 * II, &As[bb][2048 + wv * 512]);
    gl_lds16(Bp, &Bs[bb][wv * 512]);
    gl_lds16(Bp + (size_t)64 * II, &Bs[bb][2048 + wv * 512]);
  };
  auto compute = [&](int bb) {
    h8 af[4], bf[4];
#pragma unroll
    for (int m = 0; m < 4; ++m) af[m] = *(const h8*)&As[bb][swzE(wm + m * 16 + ra, kq)];
#pragma unroll
    for (int n = 0; n < 4; ++n) bf[n] = *(const h8*)&Bs[bb][swzE(wn + n * 16 + ra, kq)];
#pragma unroll
    for (int m = 0; m < 4; ++m)
#pragma unroll
      for (int n = 0; n < 4; ++n)
        acc[m][n] = __builtin_amdgcn_mfma_f32_16x16x32_f16(af[m], bf[n], acc[m][n], 0, 0, 0);
  };

  const int TSTEPS = 3 * (II / 32);  // 384
  stage(0, 0);
  __syncthreads();
  int cur = 0;
  for (int t = 0; t < TSTEPS; ++t) {
    if (t + 1 < TSTEPS) stage(cur ^ 1, t + 1);
    compute(cur);
    __syncthreads();
    cur ^= 1;
  }

  float* ob = out + (size_t)b * SS * HH;
  const int rr = wm + (lane >> 4) * 4;
  const int cc = n0 + wn + ra;
#pragma unroll
  for (int m = 0; m < 4; ++m)
#pragma unroll
    for (int n = 0; n < 4; ++n)
#pragma unroll
      for (int r = 0; r < 4; ++r)
        ob[(size_t)(m0 + rr + m * 16 + r) * HH + cc + n * 16] = acc[m][n][r];
}

// ---------------- host ----------------
extern "C" void kernel_launch(void* const* d_in, const int* in_sizes, int n_in,
                              void* d_out, int out_size, void* d_ws, size_t ws_size,
                              hipStream_t stream) {
  (void)in_sizes; (void)n_in; (void)out_size;
  const float* x = (const float*)d_in[0];
  const float* router_logits = (const float*)d_in[1];
  const float* skill_gate = (const float*)d_in[2];
  const float* skill_up = (const float*)d_in[3];
  const float* skill_down = (const float*)d_in[4];
  const float* shared_gate = (const float*)d_in[5];
  const float* shared_up = (const float*)d_in[6];
  const float* shared_down = (const float*)d_in[7];
  float* out = (float*)d_out;

  char* ws = (char*)d_ws;
  size_t off = 0;
  auto alloc = [&](size_t bytes) -> void* {
    void* p = ws + off;
    off += (bytes + 255) & ~(size_t)255;
    return p;
  };
  _Float16* xf  = (_Float16*)alloc((size_t)BB * SS * HH * 2);
  _Float16* sgT = (_Float16*)alloc((size_t)EE * II * HH * 2);
  _Float16* suT = (_Float16*)alloc((size_t)EE * II * HH * 2);
  _Float16* sdT = (_Float16*)alloc((size_t)EE * HH * II * 2);
  _Float16* shgT = (_Float16*)alloc((size_t)II * HH * 2);
  _Float16* shuT = (_Float16*)alloc((size_t)II * HH * 2);
  _Float16* shdT = (_Float16*)alloc((size_t)HH * II * 2);
  int* sel = (int*)alloc(BB * 2 * sizeof(int));
  float* wsel = (float*)alloc(BB * 2 * sizeof(float));

  const size_t hbytes1 = (size_t)3 * SS * II * 2;  // per-batch h (12.6 MB)
  int chunk = 64;
  while (chunk > 1 && off + (size_t)chunk * hbytes1 > ws_size) chunk >>= 1;
  if (off + (size_t)chunk * hbytes1 > ws_size) return;  // ws too small: fail clean
  _Float16* hbuf = (_Float16*)(ws + off);

  router_kernel<<<1, 64, 0, stream>>>(router_logits, sel, wsel);
  cvt_x_kernel<<<(BB * SS * HH) / 8 / 256, 256, 0, stream>>>(x, xf);
  tcvt_kernel<<<dim3(II / 32, HH / 32, EE), 256, 0, stream>>>(skill_gate, sgT, HH, II);
  tcvt_kernel<<<dim3(II / 32, HH / 32, EE), 256, 0, stream>>>(skill_up, suT, HH, II);
  tcvt_kernel<<<dim3(HH / 32, II / 32, EE), 256, 0, stream>>>(skill_down, sdT, II, HH);
  tcvt_kernel<<<dim3(II / 32, HH / 32, 1), 256, 0, stream>>>(shared_gate, shgT, HH, II);
  tcvt_kernel<<<dim3(II / 32, HH / 32, 1), 256, 0, stream>>>(shared_up, shuT, HH, II);
  tcvt_kernel<<<dim3(HH / 32, II / 32, 1), 256, 0, stream>>>(shared_down, shdT, II, HH);

  for (int b0 = 0; b0 < BB; b0 += chunk) {
    moe_up_kernel<<<dim3(SS / 128, II / 128, chunk * 3), 256, 0, stream>>>(
        xf, sgT, suT, shgT, shuT, sel, wsel, hbuf, b0);
    moe_down_kernel<<<dim3(SS / 128, HH / 128, chunk), 256, 0, stream>>>(
        hbuf, sdT, shdT, sel, out, b0);
  }
}

// Round 5
// 3491.996 us; speedup vs baseline: 1.4742x; 1.4742x over previous
//
#include <hip/hip_runtime.h>
#include <hip/hip_fp16.h>

#define BB 64
#define SS 512
#define HH 1024
#define II 4096
#define EE 8

typedef _Float16 h8 __attribute__((ext_vector_type(8)));
typedef _Float16 h4 __attribute__((ext_vector_type(4)));
typedef float f4 __attribute__((ext_vector_type(4)));

typedef const __attribute__((address_space(1))) void* gas_t;
typedef __attribute__((address_space(3))) void* las_t;

__device__ __forceinline__ void gl_lds16(const void* g, void* l) {
  // async global->LDS, 16B per lane; LDS dest = wave-uniform base + lane*16
  __builtin_amdgcn_global_load_lds((gas_t)g, (las_t)l, 16, 0, 0);
}

// swizzled ELEMENT (fp16) offset into a [rows][32] fp16 tile.
// Staging puts global k-octet (s ^ ((row>>1)&3)) at LDS slot s; this inverts it.
__device__ __forceinline__ int swzE(int row, int kslot) {
  return row * 32 + (((kslot ^ (row >> 1)) & 3) << 3);
}

// T1: XCD-aware flat-block-id swizzle; requires nwg % 8 == 0 (always true here).
__device__ __forceinline__ int xcd_swz(int orig, int nwg) {
  return (orig & 7) * (nwg >> 3) + (orig >> 3);
}

// fast gelu(tanh-approx): g * sigmoid(1.5957692*(g + 0.044715 g^3))
__device__ __forceinline__ float fast_gelu(float g) {
  float t = 1.5957691216057308f * (g + 0.044715f * g * g * g);
  return g * __builtin_amdgcn_rcpf(1.0f + __expf(-t));
}

// ---------------- router: softmax -> top2 -> renormalize ----------------
__global__ void router_kernel(const float* __restrict__ logits,
                              int* __restrict__ sel, float* __restrict__ wsel) {
  int b = threadIdx.x;
  if (b >= BB) return;
  float l[EE];
  float mx = -1e30f;
  for (int e = 0; e < EE; ++e) { l[e] = logits[b * EE + e]; mx = fmaxf(mx, l[e]); }
  for (int e = 0; e < EE; ++e) l[e] = __expf(l[e] - mx);
  int i0 = 0;
  for (int e = 1; e < EE; ++e) if (l[e] > l[i0]) i0 = e;
  int i1 = (i0 == 0) ? 1 : 0;
  for (int e = 0; e < EE; ++e) if (e != i0 && l[e] > l[i1]) i1 = e;
  float t = l[i0] + l[i1];
  sel[b * 2 + 0] = i0; sel[b * 2 + 1] = i1;
  wsel[b * 2 + 0] = l[i0] / t; wsel[b * 2 + 1] = l[i1] / t;
}

// ---------------- x fp32 -> fp16 ----------------
__global__ void __launch_bounds__(256) cvt_x_kernel(const float* __restrict__ src,
                                                    _Float16* __restrict__ dst) {
  int i = blockIdx.x * 256 + threadIdx.x;
  const float4* s4 = (const float4*)src;
  float4 a = s4[2 * i], b = s4[2 * i + 1];
  h8 o = {(_Float16)a.x, (_Float16)a.y, (_Float16)a.z, (_Float16)a.w,
          (_Float16)b.x, (_Float16)b.y, (_Float16)b.z, (_Float16)b.w};
  *((h8*)dst + i) = o;
}

// ---------------- tiled transpose + fp32->fp16: src[R][C] -> dst[C][R] ----------------
__global__ void __launch_bounds__(256) tcvt_kernel(const float* __restrict__ src,
                                                   _Float16* __restrict__ dst,
                                                   int R, int C) {
  __shared__ float tile[32][33];
  size_t msz = (size_t)R * C;
  src += (size_t)blockIdx.z * msz;
  dst += (size_t)blockIdx.z * msz;
  int c0 = blockIdx.x * 32, r0 = blockIdx.y * 32;
  int t = threadIdx.x;
  int ir = t >> 3, ic = (t & 7) * 4;
  float4 v = *(const float4*)(src + (size_t)(r0 + ir) * C + c0 + ic);
  tile[ir][ic + 0] = v.x; tile[ir][ic + 1] = v.y;
  tile[ir][ic + 2] = v.z; tile[ir][ic + 3] = v.w;
  __syncthreads();
  h4 o;
  o[0] = (_Float16)tile[ic + 0][ir];
  o[1] = (_Float16)tile[ic + 1][ir];
  o[2] = (_Float16)tile[ic + 2][ir];
  o[3] = (_Float16)tile[ic + 3][ir];
  *(h4*)(dst + (size_t)(c0 + ir) * R + r0 + ic) = o;
}

// ---------------- up: G = x@Wg, U = x@Wu, h = wgt * gelu(G) * U ----------------
// 128x128 tile (G and U), BK=32, 4 waves.
// Depth-3 static pipeline, counted vmcnt(12) (never 0 in loop), raw barriers.
__global__ void __launch_bounds__(256, 2)
moe_up_kernel(const _Float16* __restrict__ xf,
              const _Float16* __restrict__ sgT, const _Float16* __restrict__ suT,
              const _Float16* __restrict__ shgT, const _Float16* __restrict__ shuT,
              const int* __restrict__ sel, const float* __restrict__ wsel,
              _Float16* __restrict__ hbuf, int b0) {
  __shared__ _Float16 As[3][128 * 32];
  __shared__ _Float16 Bgs[3][128 * 32];
  __shared__ _Float16 Bus[3][128 * 32];

  const int nz = gridDim.z;
  int orig = blockIdx.x + 4 * (blockIdx.y + 32 * blockIdx.z);
  int swz = xcd_swz(orig, 128 * nz);
  const int bm = swz & 3, bn = (swz >> 2) & 31, task = swz >> 7;

  const int cb = task / 3, slot = task - cb * 3;
  const int b = b0 + cb;
  const _Float16 *Wg, *Wu;
  float wgt;
  if (slot < 2) {
    int e = sel[b * 2 + slot];
    wgt = wsel[b * 2 + slot];
    Wg = sgT + (size_t)e * II * HH;
    Wu = suT + (size_t)e * II * HH;
  } else {
    wgt = 1.0f; Wg = shgT; Wu = shuT;
  }
  const _Float16* A = xf + (size_t)b * SS * HH;
  const int m0 = bm * 128, n0 = bn * 128;
  const int tid = threadIdx.x, lane = tid & 63, wv = tid >> 6;
  const int wm = (wv >> 1) * 64, wn = (wv & 1) * 64;

  const int sr = tid >> 2;
  const int ksl = (tid & 3) ^ ((tid >> 3) & 3);
  const _Float16* ga0 = A + (size_t)(m0 + sr) * HH + ksl * 8;
  const _Float16* ga1 = A + (size_t)(m0 + 64 + sr) * HH + ksl * 8;
  const _Float16* gg0 = Wg + (size_t)(n0 + sr) * HH + ksl * 8;
  const _Float16* gg1 = Wg + (size_t)(n0 + 64 + sr) * HH + ksl * 8;
  const _Float16* gu0 = Wu + (size_t)(n0 + sr) * HH + ksl * 8;
  const _Float16* gu1 = Wu + (size_t)(n0 + 64 + sr) * HH + ksl * 8;

  const int ra = lane & 15, kq = lane >> 4;
  // loop-invariant swizzled LDS element offsets
  int aoff[4], boff[4];
#pragma unroll
  for (int m = 0; m < 4; ++m) aoff[m] = swzE(wm + m * 16 + ra, kq);
#pragma unroll
  for (int n = 0; n < 4; ++n) boff[n] = swzE(wn + n * 16 + ra, kq);

  f4 accG[4][4] = {};
  f4 accU[4][4] = {};

#define UP_STAGE(B, K0) do { int _k = (K0);                          \
    gl_lds16(ga0 + _k, &As[B][wv * 512]);                            \
    gl_lds16(ga1 + _k, &As[B][2048 + wv * 512]);                     \
    gl_lds16(gg0 + _k, &Bgs[B][wv * 512]);                           \
    gl_lds16(gg1 + _k, &Bgs[B][2048 + wv * 512]);                    \
    gl_lds16(gu0 + _k, &Bus[B][wv * 512]);                           \
    gl_lds16(gu1 + _k, &Bus[B][2048 + wv * 512]);                    \
  } while (0)

#define UP_PHASE(B, PFT) do {                                        \
    asm volatile("s_waitcnt vmcnt(12)" ::: "memory");                \
    __builtin_amdgcn_s_barrier();                                    \
    h8 af[4], bgf[4], buf_[4];                                       \
    _Pragma("unroll") for (int m = 0; m < 4; ++m)                    \
      af[m] = *(const h8*)&As[B][aoff[m]];                           \
    _Pragma("unroll") for (int n = 0; n < 4; ++n) {                  \
      bgf[n]  = *(const h8*)&Bgs[B][boff[n]];                        \
      buf_[n] = *(const h8*)&Bus[B][boff[n]];                        \
    }                                                                \
    asm volatile("s_waitcnt lgkmcnt(0)" ::: "memory");               \
    __builtin_amdgcn_sched_barrier(0);                               \
    __builtin_amdgcn_s_barrier();                                    \
    UP_STAGE(B, (PFT) * 32);                                         \
    _Pragma("unroll") for (int m = 0; m < 4; ++m)                    \
      _Pragma("unroll") for (int n = 0; n < 4; ++n) {                \
        accG[m][n] = __builtin_amdgcn_mfma_f32_16x16x32_f16(af[m], bgf[n],  accG[m][n], 0, 0, 0); \
        accU[m][n] = __builtin_amdgcn_mfma_f32_16x16x32_f16(af[m], buf_[n], accU[m][n], 0, 0, 0); \
      }                                                              \
  } while (0)

  // prologue: fill 3 stages (18 loads in flight)
  UP_STAGE(0, 0);
  UP_STAGE(1, 32);
  UP_STAGE(2, 64);
  // 32 K-steps total; triples for 0..29, tail 30,31 (clamped dead prefetch)
  for (int t = 0; t < 30; t += 3) {
    int p0 = t + 3 > 31 ? 31 : t + 3;
    int p1 = t + 4 > 31 ? 31 : t + 4;
    int p2 = t + 5 > 31 ? 31 : t + 5;
    UP_PHASE(0, p0);
    UP_PHASE(1, p1);
    UP_PHASE(2, p2);
  }
  UP_PHASE(0, 31);
  UP_PHASE(1, 31);
#undef UP_PHASE
#undef UP_STAGE

  // epilogue: h = wgt * gelu(G) * U -> fp16
  _Float16* hb = hbuf + (size_t)task * SS * II;
  const int rr = wm + (lane >> 4) * 4;
  const int cc = n0 + wn + ra;
#pragma unroll
  for (int m = 0; m < 4; ++m)
#pragma unroll
    for (int n = 0; n < 4; ++n)
#pragma unroll
      for (int r = 0; r < 4; ++r) {
        float g = accG[m][n][r];
        float u = accU[m][n][r];
        int row = m0 + rr + m * 16 + r;
        int col = cc + n * 16;
        hb[(size_t)row * II + col] = (_Float16)(wgt * fast_gelu(g) * u);
      }
}

// ---------------- down: out[b] = sum_slot h_slot @ Wd_slot ----------------
// 128x128 tile, BK=32, flattened 384 steps over 3 slots, depth-3 pipeline.
__global__ void __launch_bounds__(256, 2)
moe_down_kernel(const _Float16* __restrict__ hbuf,
                const _Float16* __restrict__ sdT, const _Float16* __restrict__ shdT,
                const int* __restrict__ sel,
                float* __restrict__ out, int b0) {
  __shared__ _Float16 As[3][128 * 32];
  __shared__ _Float16 Bs[3][128 * 32];

  const int nz = gridDim.z;
  int orig = blockIdx.x + 4 * (blockIdx.y + 8 * blockIdx.z);
  int swz = xcd_swz(orig, 32 * nz);
  const int bm = swz & 3, bn = (swz >> 2) & 7, cb = swz >> 5;
  const int b = b0 + cb;

  const int m0 = bm * 128, n0 = bn * 128;
  const int tid = threadIdx.x, lane = tid & 63, wv = tid >> 6;
  const int wm = (wv >> 1) * 64, wn = (wv & 1) * 64;
  const int sr = tid >> 2;
  const int ksl = (tid & 3) ^ ((tid >> 3) & 3);
  const int ra = lane & 15, kq = lane >> 4;

  int aoff[4], boff[4];
#pragma unroll
  for (int m = 0; m < 4; ++m) aoff[m] = swzE(wm + m * 16 + ra, kq);
#pragma unroll
  for (int n = 0; n < 4; ++n) boff[n] = swzE(wn + n * 16 + ra, kq);

  const size_t slotStride = (size_t)SS * II;
  const _Float16* a0 = hbuf + (size_t)(cb * 3) * slotStride + (size_t)(m0 + sr) * II + ksl * 8;
  const size_t bof = (size_t)(n0 + sr) * II + ksl * 8;
  const _Float16* pb0 = sdT + (size_t)sel[b * 2 + 0] * HH * II + bof;
  const _Float16* pb1 = sdT + (size_t)sel[b * 2 + 1] * HH * II + bof;
  const _Float16* pb2 = shdT + bof;

  f4 acc[4][4] = {};

#define DN_STAGE(B, T) do { int _t = (T);                            \
    int _sl = _t >> 7; int _k0 = (_t & 127) << 5;                    \
    const _Float16* _Ap = a0 + (size_t)_sl * slotStride + _k0;       \
    const _Float16* _Bp = (_sl == 0 ? pb0 : (_sl == 1 ? pb1 : pb2)) + _k0; \
    gl_lds16(_Ap, &As[B][wv * 512]);                                 \
    gl_lds16(_Ap + (size_t)64 * II, &As[B][2048 + wv * 512]);        \
    gl_lds16(_Bp, &Bs[B][wv * 512]);                                 \
    gl_lds16(_Bp + (size_t)64 * II, &Bs[B][2048 + wv * 512]);        \
  } while (0)

#define DN_PHASE(B, PFT) do {                                        \
    asm volatile("s_waitcnt vmcnt(8)" ::: "memory");                 \
    __builtin_amdgcn_s_barrier();                                    \
    h8 af[4], bf[4];                                                 \
    _Pragma("unroll") for (int m = 0; m < 4; ++m)                    \
      af[m] = *(const h8*)&As[B][aoff[m]];                           \
    _Pragma("unroll") for (int n = 0; n < 4; ++n)                    \
      bf[n] = *(const h8*)&Bs[B][boff[n]];                           \
    asm volatile("s_waitcnt lgkmcnt(0)" ::: "memory");               \
    __builtin_amdgcn_sched_barrier(0);                               \
    __builtin_amdgcn_s_barrier();                                    \
    DN_STAGE(B, PFT);                                                \
    _Pragma("unroll") for (int m = 0; m < 4; ++m)                    \
      _Pragma("unroll") for (int n = 0; n < 4; ++n)                  \
        acc[m][n] = __builtin_amdgcn_mfma_f32_16x16x32_f16(af[m], bf[n], acc[m][n], 0, 0, 0); \
  } while (0)

  // 384 steps (3 slots x 128); prologue fills 3
  DN_STAGE(0, 0);
  DN_STAGE(1, 1);
  DN_STAGE(2, 2);
  for (int t = 0; t < 384; t += 3) {
    int p0 = t + 3 > 383 ? 383 : t + 3;
    int p1 = t + 4 > 383 ? 383 : t + 4;
    int p2 = t + 5 > 383 ? 383 : t + 5;
    DN_PHASE(0, p0);
    DN_PHASE(1, p1);
    DN_PHASE(2, p2);
  }
#undef DN_PHASE
#undef DN_STAGE

  float* ob = out + (size_t)b * SS * HH;
  const int rr = wm + (lane >> 4) * 4;
  const int cc = n0 + wn + ra;
#pragma unroll
  for (int m = 0; m < 4; ++m)
#pragma unroll
    for (int n = 0; n < 4; ++n)
#pragma unroll
      for (int r = 0; r < 4; ++r)
        ob[(size_t)(m0 + rr + m * 16 + r) * HH + cc + n * 16] = acc[m][n][r];
}

// ---------------- host ----------------
extern "C" void kernel_launch(void* const* d_in, const int* in_sizes, int n_in,
                              void* d_out, int out_size, void* d_ws, size_t ws_size,
                              hipStream_t stream) {
  (void)in_sizes; (void)n_in; (void)out_size;
  const float* x = (const float*)d_in[0];
  const float* router_logits = (const float*)d_in[1];
  const float* skill_gate = (const float*)d_in[2];
  const float* skill_up = (const float*)d_in[3];
  const float* skill_down = (const float*)d_in[4];
  const float* shared_gate = (const float*)d_in[5];
  const float* shared_up = (const float*)d_in[6];
  const float* shared_down = (const float*)d_in[7];
  float* out = (float*)d_out;

  char* ws = (char*)d_ws;
  size_t off = 0;
  auto alloc = [&](size_t bytes) -> void* {
    void* p = ws + off;
    off += (bytes + 255) & ~(size_t)255;
    return p;
  };
  _Float16* xf  = (_Float16*)alloc((size_t)BB * SS * HH * 2);
  _Float16* sgT = (_Float16*)alloc((size_t)EE * II * HH * 2);
  _Float16* suT = (_Float16*)alloc((size_t)EE * II * HH * 2);
  _Float16* sdT = (_Float16*)alloc((size_t)EE * HH * II * 2);
  _Float16* shgT = (_Float16*)alloc((size_t)II * HH * 2);
  _Float16* shuT = (_Float16*)alloc((size_t)II * HH * 2);
  _Float16* shdT = (_Float16*)alloc((size_t)HH * II * 2);
  int* sel = (int*)alloc(BB * 2 * sizeof(int));
  float* wsel = (float*)alloc(BB * 2 * sizeof(float));

  const size_t hbytes1 = (size_t)3 * SS * II * 2;  // per-batch h (12.6 MB)
  int chunk = 64;
  while (chunk > 1 && off + (size_t)chunk * hbytes1 > ws_size) chunk >>= 1;
  if (off + (size_t)chunk * hbytes1 > ws_size) return;  // ws too small: fail clean
  _Float16* hbuf = (_Float16*)(ws + off);

  router_kernel<<<1, 64, 0, stream>>>(router_logits, sel, wsel);
  cvt_x_kernel<<<(BB * SS * HH) / 8 / 256, 256, 0, stream>>>(x, xf);
  tcvt_kernel<<<dim3(II / 32, HH / 32, EE), 256, 0, stream>>>(skill_gate, sgT, HH, II);
  tcvt_kernel<<<dim3(II / 32, HH / 32, EE), 256, 0, stream>>>(skill_up, suT, HH, II);
  tcvt_kernel<<<dim3(HH / 32, II / 32, EE), 256, 0, stream>>>(skill_down, sdT, II, HH);
  tcvt_kernel<<<dim3(II / 32, HH / 32, 1), 256, 0, stream>>>(shared_gate, shgT, HH, II);
  tcvt_kernel<<<dim3(II / 32, HH / 32, 1), 256, 0, stream>>>(shared_up, shuT, HH, II);
  tcvt_kernel<<<dim3(HH / 32, II / 32, 1), 256, 0, stream>>>(shared_down, shdT, II, HH);

  for (int b0 = 0; b0 < BB; b0 += chunk) {
    moe_up_kernel<<<dim3(SS / 128, II / 128, chunk * 3), 256, 0, stream>>>(
        xf, sgT, suT, shgT, shuT, sel, wsel, hbuf, b0);
    moe_down_kernel<<<dim3(SS / 128, HH / 128, chunk), 256, 0, stream>>>(
        hbuf, sdT, shdT, sel, out, b0);
  }
}